// Round 2
// baseline (199.671 us; speedup 1.0000x reference)
//
#include <hip/hip_runtime.h>
#include <stdint.h>

// ---------------------------------------------------------------------------
// AttentionBlock: GroupNorm(32) -> qkv 1x1 -> 8-head attention (T=1024,ch=64)
//                 -> proj 1x1 + residual.  B=8, C=512, T=1024. fp32 I/O,
//                 bf16 MFMA internally. Transpose-free dataflow:
//   xnT[b][t][c]  (t-major activations)
//   GEMM-QK: D[t][o'] = xnT x Wqk^T   -> qkT[b][t][ Qall(512) | Kall(512) ]
//   GEMM-V : D[cv][t] = Wv x xn       -> vbuf[b][cv][t] (channel-major)
//   attn   : S'[s][t]=mfma(K^T,Q^T); PV: D[c][t]=mfma(V, P'); out attT[b][t][c]
//   proj   : D[o][t] = Wp x att + bias + x -> d_out
// Every MFMA fragment is a plain ds_read_b64 pair; A and B frags use the same
// slot->k map so any true HW k-permutation cancels.
// ---------------------------------------------------------------------------

typedef float  f32x4  __attribute__((ext_vector_type(4)));
typedef short  s16x4  __attribute__((ext_vector_type(4)));
typedef short  s16x8  __attribute__((ext_vector_type(8)));
typedef __bf16 bf16x8 __attribute__((ext_vector_type(8)));

__device__ __forceinline__ f32x4 mfma_bf16_16x16x32(s16x8 a, s16x8 b, f32x4 c){
  return __builtin_amdgcn_mfma_f32_16x16x32_bf16(
      __builtin_bit_cast(bf16x8, a), __builtin_bit_cast(bf16x8, b), c, 0, 0, 0);
}

__device__ __forceinline__ s16x8 cat8(s16x4 lo, s16x4 hi){
  return __builtin_shufflevector(lo, hi, 0,1,2,3,4,5,6,7);
}

// fp32 -> bf16 bits, round-nearest-even (finite values only)
__device__ __forceinline__ short f2bf(float v){
  uint32_t u = __builtin_bit_cast(uint32_t, v);
  uint32_t r = (u + 0x7FFFu + ((u >> 16) & 1u)) >> 16;
  return (short)r;
}

// ---------------------------------------------------------------------------
// GroupNorm stats: one block per (b,g); group = 16 contiguous channels * 1024
__global__ __launch_bounds__(256) void gn_stats_kernel(const float* __restrict__ x,
                                                       float2* __restrict__ stats){
  __shared__ float ss[256], sq[256];
  const int bg = blockIdx.x;
  const float4* base = (const float4*)(x + (size_t)bg * 16384);
  float s = 0.f, q = 0.f;
  #pragma unroll
  for (int i = 0; i < 16; ++i){
    float4 v = base[threadIdx.x + i*256];
    s += v.x + v.y + v.z + v.w;
    q += v.x*v.x + v.y*v.y + v.z*v.z + v.w*v.w;
  }
  ss[threadIdx.x] = s; sq[threadIdx.x] = q;
  __syncthreads();
  for (int off = 128; off > 0; off >>= 1){
    if (threadIdx.x < off){ ss[threadIdx.x] += ss[threadIdx.x+off];
                            sq[threadIdx.x] += sq[threadIdx.x+off]; }
    __syncthreads();
  }
  if (threadIdx.x == 0){
    float mu  = ss[0] * (1.f/16384.f);
    float var = sq[0] * (1.f/16384.f) - mu*mu;   // biased (matches jnp.var)
    stats[bg] = make_float2(mu, rsqrtf(var + 1e-5f));
  }
}

// normalize + affine -> bf16 xnT[b][t][c] (transposed via LDS tile)
__global__ __launch_bounds__(256) void gn_norm_t_kernel(const float* __restrict__ x,
    const float* __restrict__ w, const float* __restrict__ bia,
    const float2* __restrict__ stats, short* __restrict__ xnT){
  const int t0 = blockIdx.x * 64, b = blockIdx.y;
  const int tid = threadIdx.x;
  __shared__ short L[64*68];                 // [c][t] pad->68 (8B aligned rows)
  const float* xb = x   + (size_t)b * 524288;
  short*       ob = xnT + (size_t)b * 524288;
  for (int cc = 0; cc < 8; ++cc){
    #pragma unroll
    for (int i = 0; i < 4; ++i){
      const int f  = tid + i*256;            // 0..1023
      const int cl = f >> 4, t4 = (f & 15) * 4;
      const int ch = cc*64 + cl;
      const float2 st = stats[b*32 + (ch >> 4)];
      const float sc = st.y * w[ch];
      const float sh = bia[ch] - st.x * sc;
      float4 v = *(const float4*)(xb + (size_t)ch*1024 + t0 + t4);
      s16x4 o;
      o[0]=f2bf(v.x*sc+sh); o[1]=f2bf(v.y*sc+sh); o[2]=f2bf(v.z*sc+sh); o[3]=f2bf(v.w*sc+sh);
      *(s16x4*)&L[cl*68 + t4] = o;
    }
    __syncthreads();
    #pragma unroll
    for (int i = 0; i < 2; ++i){
      const int g  = tid + i*256;            // 0..511
      const int tl = g >> 3, c8 = g & 7;
      s16x8 o;
      #pragma unroll
      for (int j = 0; j < 8; ++j) o[j] = L[(c8*8 + j)*68 + tl];
      *(s16x8*)(ob + (size_t)(t0 + tl)*512 + cc*64 + c8*8) = o;
    }
    __syncthreads();
  }
}

__global__ __launch_bounds__(256) void cvt_bf16_kernel(const float* __restrict__ in,
                                                       short* __restrict__ out, int n8){
  const int i = blockIdx.x*256 + threadIdx.x;
  if (i >= n8) return;
  const float4* p = (const float4*)in + (size_t)i*2;
  float4 a = p[0], b = p[1];
  s16x8 o;
  o[0]=f2bf(a.x); o[1]=f2bf(a.y); o[2]=f2bf(a.z); o[3]=f2bf(a.w);
  o[4]=f2bf(b.x); o[5]=f2bf(b.y); o[6]=f2bf(b.z); o[7]=f2bf(b.w);
  *(s16x8*)(out + (size_t)i*8) = o;
}

// ---------------------------------------------------------------------------
// Unified K=512 GEMM, 128x128 tile, BK=32, 4 waves (2x2), 4x4 16x16 frags/wave.
// Both LDS tiles are [row][32k] (pad 40); A-frag rows -> D rows, B-frag rows ->
// D cols; frag reads are ds_read_b64 pairs with identical k-maps.
// MODE 0 (QK): A=xnT rows t, B=Wqk rows o' (head-perm), out qkT bf16 [t][1024]
// MODE 1 (V):  A=Wv rows cv (perm),  B=xnT rows t,     out vbuf bf16 [cv][1024]
// MODE 2 (PR): A=Wp rows o,          B=attT rows t,    out f32 [o][1024]+b+res
template<int MODE>
__global__ __launch_bounds__(256) void gemm_k512(const short* __restrict__ W,
    const short* __restrict__ act, const float* __restrict__ bias,
    const float* __restrict__ resid, void* __restrict__ outp){
  const int b  = blockIdx.z;
  const int m0 = blockIdx.y * 128;
  const int n0 = blockIdx.x * 128;
  const int tid  = threadIdx.x;
  const int lane = tid & 63, w = tid >> 6;
  const int wm = w >> 1, wn = w & 1;
  const int lm = lane & 15, lb = lane >> 4;

  __shared__ short As[2][128*40];
  __shared__ short Bs[2][128*40];

  const short* actb = act + (size_t)b * 524288;

  auto arow = [&](int r) -> const short* {
    if constexpr (MODE == 0){
      return actb + (size_t)(m0 + r) * 512;
    } else if constexpr (MODE == 1){
      const int m = m0 + r;
      return W + (size_t)(192*(m>>6) + 128 + (m&63)) * 512;
    } else {
      return W + (size_t)(m0 + r) * 512;
    }
  };
  auto brow = [&](int r) -> const short* {
    if constexpr (MODE == 0){
      const int o = n0 + r;
      return W + (size_t)(192*((o>>6)&7) + (o&63) + ((o>=512)?64:0)) * 512;
    } else {
      return actb + (size_t)(n0 + r) * 512;
    }
  };

  uint4 areg[2], breg[2];
  auto load_regs = [&](int t){
    const int k0 = t * 32;
    #pragma unroll
    for (int i = 0; i < 2; ++i){
      const int c = tid + i*256;
      const int r = c >> 2, off = (c & 3) * 8;
      areg[i] = *(const uint4*)(arow(r) + k0 + off);
      breg[i] = *(const uint4*)(brow(r) + k0 + off);
    }
  };
  auto write_lds = [&](int buf){
    #pragma unroll
    for (int i = 0; i < 2; ++i){
      const int c = tid + i*256;
      const int r = c >> 2, off = (c & 3) * 8;
      *(uint4*)&As[buf][r*40 + off] = areg[i];
      *(uint4*)&Bs[buf][r*40 + off] = breg[i];
    }
  };

  f32x4 acc[4][4] = {};
  load_regs(0);
  write_lds(0);

  for (int t = 0; t < 16; ++t){
    if (t + 1 < 16) load_regs(t + 1);
    __syncthreads();
    const int buf = t & 1;

    s16x8 af[4], bf[4];
    #pragma unroll
    for (int ms = 0; ms < 4; ++ms){
      const short* p = &As[buf][(wm*64 + ms*16 + lm)*40 + 4*lb];
      af[ms] = cat8(*(const s16x4*)p, *(const s16x4*)(p + 16));
    }
    #pragma unroll
    for (int ns = 0; ns < 4; ++ns){
      const short* p = &Bs[buf][(wn*64 + ns*16 + lm)*40 + 4*lb];
      bf[ns] = cat8(*(const s16x4*)p, *(const s16x4*)(p + 16));
    }
    #pragma unroll
    for (int ns = 0; ns < 4; ++ns)
      #pragma unroll
      for (int ms = 0; ms < 4; ++ms)
        acc[ms][ns] = mfma_bf16_16x16x32(af[ms], bf[ns], acc[ms][ns]);

    if (t + 1 < 16) write_lds((t + 1) & 1);
  }

  // C/D: col = lane&15, row = 4*(lane>>4) + reg   (m89)
  const int mo = m0 + wm*64, no = n0 + wn*64;
  if constexpr (MODE == 0){
    short* out = (short*)outp + (size_t)b * 1048576;
    float bn[4];
    #pragma unroll
    for (int ns = 0; ns < 4; ++ns){
      const int o = no + ns*16 + lm;
      bn[ns] = bias[192*((o>>6)&7) + (o&63) + ((o>=512)?64:0)];
    }
    #pragma unroll
    for (int ms = 0; ms < 4; ++ms)
      #pragma unroll
      for (int ns = 0; ns < 4; ++ns)
        #pragma unroll
        for (int r = 0; r < 4; ++r){
          const int m = mo + ms*16 + 4*lb + r;
          const int n = no + ns*16 + lm;
          out[(size_t)m*1024 + n] = f2bf(acc[ms][ns][r] + bn[ns]);
        }
  } else if constexpr (MODE == 1){
    short* out = (short*)outp + (size_t)b * 524288;
    float bm[16];
    #pragma unroll
    for (int ms = 0; ms < 4; ++ms)
      #pragma unroll
      for (int r = 0; r < 4; ++r){
        const int m = mo + ms*16 + 4*lb + r;
        bm[ms*4+r] = bias[192*(m>>6) + 128 + (m&63)];
      }
    #pragma unroll
    for (int ms = 0; ms < 4; ++ms)
      #pragma unroll
      for (int ns = 0; ns < 4; ++ns)
        #pragma unroll
        for (int r = 0; r < 4; ++r){
          const int m = mo + ms*16 + 4*lb + r;
          const int n = no + ns*16 + lm;
          out[(size_t)m*1024 + n] = f2bf(acc[ms][ns][r] + bm[ms*4+r]);
        }
  } else {
    float* out = (float*)outp + (size_t)b * 524288;
    const float* xr = resid + (size_t)b * 524288;
    #pragma unroll
    for (int ms = 0; ms < 4; ++ms)
      #pragma unroll
      for (int ns = 0; ns < 4; ++ns)
        #pragma unroll
        for (int r = 0; r < 4; ++r){
          const int m = mo + ms*16 + 4*lb + r;
          const int n = no + ns*16 + lm;
          out[(size_t)m*1024 + n] = acc[ms][ns][r] + bias[m] + xr[(size_t)m*1024 + n];
        }
  }
}

// ---------------------------------------------------------------------------
// Attention: block = (b,h) x 64-t chunk; 4 waves; wave w owns t = w*16+lm.
// S'[s][t] = mfma(A = K^T rows (Ks[s][c]), B = Q^T rows (Qs[t][c])).
// Online softmax over s: 16 in-lane values + shfl_xor(16,32).
// PV: D[c][t] = mfma(A = V rows (Vs[c][s]), B = P' in-register).
// Epilogue: [c][t] regs -> LDS (reuse Qs) -> attT[b][t][c] coalesced.
__global__ __launch_bounds__(256) void attn2_kernel(const short* __restrict__ qkT,
    const short* __restrict__ vbuf, short* __restrict__ attT){
  const int tc = blockIdx.x, bh = blockIdx.y;
  const int b = bh >> 3, h = bh & 7;
  const int tid = threadIdx.x;
  const int lane = tid & 63, w = tid >> 6;
  const int lm = lane & 15, lb = lane >> 4;
  const int t0 = tc * 64;

  const short* qb = qkT + (size_t)b*1048576 + h*64;          // + t*1024
  const short* kb = qkT + (size_t)b*1048576 + 512 + h*64;    // + s*1024
  const short* vb = vbuf + (size_t)b*524288 + (size_t)(h*64)*1024;  // + c*1024 + s

  __shared__ short Qs[64*72];       // [t][c] pad 72; reused as Tl in epilogue
  __shared__ short Ks[2][64*72];    // [s][c]
  __shared__ short Vs[2][64*72];    // [c][s]

  #pragma unroll
  for (int i = 0; i < 2; ++i){
    const int g = tid + i*256, r = g >> 3, c8 = g & 7;
    *(uint4*)&Qs[r*72 + c8*8] = *(const uint4*)(qb + (size_t)(t0 + r)*1024 + c8*8);
  }
  __syncthreads();

  s16x8 qf[2];
  #pragma unroll
  for (int ks = 0; ks < 2; ++ks){
    const short* p = &Qs[(w*16 + lm)*72 + ks*32 + 4*lb];
    qf[ks] = cat8(*(const s16x4*)p, *(const s16x4*)(p + 16));
  }

  uint4 kreg[2], vreg[2];
  auto load_kv = [&](int it){
    const int s0 = it * 64;
    #pragma unroll
    for (int i = 0; i < 2; ++i){
      const int g = tid + i*256, r = g >> 3, c8 = g & 7;
      kreg[i] = *(const uint4*)(kb + (size_t)(s0 + r)*1024 + c8*8);
      vreg[i] = *(const uint4*)(vb + (size_t)r*1024 + s0 + c8*8);
    }
  };
  auto write_kv = [&](int buf){
    #pragma unroll
    for (int i = 0; i < 2; ++i){
      const int g = tid + i*256, r = g >> 3, c8 = g & 7;
      *(uint4*)&Ks[buf][r*72 + c8*8] = kreg[i];
      *(uint4*)&Vs[buf][r*72 + c8*8] = vreg[i];
    }
  };

  f32x4 of[4] = {};
  float mrun = -1e30f, lrun = 0.f;

  load_kv(0);
  write_kv(0);

  for (int it = 0; it < 16; ++it){
    if (it + 1 < 16) load_kv(it + 1);
    __syncthreads();
    const int buf = it & 1;

    f32x4 sf[4] = {};
    #pragma unroll
    for (int ks = 0; ks < 2; ++ks){
      #pragma unroll
      for (int ms = 0; ms < 4; ++ms){
        const short* p = &Ks[buf][(ms*16 + lm)*72 + ks*32 + 4*lb];
        sf[ms] = mfma_bf16_16x16x32(cat8(*(const s16x4*)p, *(const s16x4*)(p+16)),
                                    qf[ks], sf[ms]);
      }
    }

    // online softmax over s; scale^2 = 1/8
    float pv[16];
    float mt = -1e30f;
    #pragma unroll
    for (int ms = 0; ms < 4; ++ms)
      #pragma unroll
      for (int r = 0; r < 4; ++r){
        const float sv = sf[ms][r] * 0.125f;
        pv[ms*4 + r] = sv;
        mt = fmaxf(mt, sv);
      }
    mt = fmaxf(mt, __shfl_xor(mt, 16, 64));
    mt = fmaxf(mt, __shfl_xor(mt, 32, 64));
    const float mnew  = fmaxf(mrun, mt);
    const float alpha = __expf(mrun - mnew);
    float ps = 0.f;
    #pragma unroll
    for (int i = 0; i < 16; ++i){ pv[i] = __expf(pv[i] - mnew); ps += pv[i]; }
    ps += __shfl_xor(ps, 16, 64);
    ps += __shfl_xor(ps, 32, 64);
    lrun = lrun * alpha + ps;
    mrun = mnew;
    #pragma unroll
    for (int cs = 0; cs < 4; ++cs)
      #pragma unroll
      for (int r = 0; r < 4; ++r) of[cs][r] *= alpha;

    #pragma unroll
    for (int ks2 = 0; ks2 < 2; ++ks2){
      s16x8 pf;
      #pragma unroll
      for (int j = 0; j < 8; ++j) pf[j] = f2bf(pv[8*ks2 + j]);
      #pragma unroll
      for (int cs = 0; cs < 4; ++cs){
        const short* p = &Vs[buf][(cs*16 + lm)*72 + ks2*32 + 4*lb];
        of[cs] = mfma_bf16_16x16x32(cat8(*(const s16x4*)p, *(const s16x4*)(p+16)),
                                    pf, of[cs]);
      }
    }
    if (it + 1 < 16) write_kv((it + 1) & 1);
  }

  // epilogue: of[cs][r] holds A_att[c = cs*16+4lb+r][t = w*16+lm]; transpose
  // through LDS (reuse Qs) and store attT[b][t][c] coalesced.
  const float inv = 1.f / lrun;
  short* Tl = Qs;
  #pragma unroll
  for (int cs = 0; cs < 4; ++cs)
    #pragma unroll
    for (int r = 0; r < 4; ++r)
      Tl[(w*16 + lm)*72 + cs*16 + 4*lb + r] = f2bf(of[cs][r] * inv);
  __syncthreads();
  short* outb = attT + (size_t)b*524288 + (size_t)t0*512 + h*64;
  #pragma unroll
  for (int i = 0; i < 2; ++i){
    const int g = tid + i*256, r = g >> 3, c8 = g & 7;
    *(uint4*)(outb + (size_t)r*512 + c8*8) = *(const uint4*)&Tl[r*72 + c8*8];
  }
}

// ---------------------------------------------------------------------------
extern "C" void kernel_launch(void* const* d_in, const int* in_sizes, int n_in,
                              void* d_out, int out_size, void* d_ws, size_t ws_size,
                              hipStream_t stream){
  const float* x      = (const float*)d_in[0];
  const float* norm_w = (const float*)d_in[1];
  const float* norm_b = (const float*)d_in[2];
  const float* qkv_w  = (const float*)d_in[3];
  const float* qkv_b  = (const float*)d_in[4];
  const float* proj_w = (const float*)d_in[5];
  const float* proj_b = (const float*)d_in[6];

  char* ws = (char*)d_ws;
  float2* stats = (float2*)(ws);                                   //   4 KB
  short*  xnT   = (short*)(ws + 4096);                             //   8 MiB
  short*  qwb   = (short*)(ws + 4096 + 8388608);                   // 1.5 MiB
  short*  pwb   = (short*)(ws + 4096 + 8388608 + 1572864);         // 0.5 MiB
  short*  qkT   = (short*)(ws + 4096 + 8388608 + 1572864 + 524288);            // 16 MiB
  short*  vbuf  = (short*)(ws + 4096 + 8388608 + 1572864 + 524288 + 16777216); //  8 MiB
  short*  attT  = (short*)(ws + 4096 + 8388608 + 1572864 + 524288 + 16777216 + 8388608); // 8 MiB

  gn_stats_kernel<<<dim3(256), dim3(256), 0, stream>>>(x, stats);
  gn_norm_t_kernel<<<dim3(16, 8), dim3(256), 0, stream>>>(x, norm_w, norm_b, stats, xnT);
  cvt_bf16_kernel<<<dim3(384), dim3(256), 0, stream>>>(qkv_w, qwb, 98304);
  cvt_bf16_kernel<<<dim3(128), dim3(256), 0, stream>>>(proj_w, pwb, 32768);
  gemm_k512<0><<<dim3(8, 8, 8), dim3(256), 0, stream>>>(qwb, xnT, qkv_b, nullptr, (void*)qkT);
  gemm_k512<1><<<dim3(8, 4, 8), dim3(256), 0, stream>>>(qwb, xnT, qkv_b, nullptr, (void*)vbuf);
  attn2_kernel<<<dim3(16, 64), dim3(256), 0, stream>>>(qkT, vbuf, attT);
  gemm_k512<2><<<dim3(8, 4, 8), dim3(256), 0, stream>>>(pwb, attT, proj_b, x, d_out);
}

// Round 3
// 161.293 us; speedup vs baseline: 1.2379x; 1.2379x over previous
//
#include <hip/hip_runtime.h>
#include <stdint.h>

// ---------------------------------------------------------------------------
// AttentionBlock: GroupNorm(32) -> qkv 1x1 -> 8-head attention (T=1024,ch=64)
//                 -> proj 1x1 + residual.  B=8, C=512, T=1024. fp32 I/O,
//                 bf16 MFMA internally.
//   xnT[b][t][c]  (t-major activations)
//   GEMM-QK: D[t][o'] = xnT x Wqk^T -> qkT[b][t][Qall|Kall]  (pre-scaled)
//   GEMM-V : D[cv][t] = Wv x xn    -> vbuf[b][cv][t]
//   attn   : flash, 128t/block, 32t/wave; S'=mfma(K^T,Q^T), PV=mfma(V,P')
//   proj   : D[o][t] = Wp x att + bias + x -> d_out
// k-map note: MFMA slot->k is a bijection that cancels between A and B, so
// QK/GEMM use the contiguous map k=8*lb+j (single ds_read_b128 per frag);
// PV uses k=4*lb+j(+16) because P' lands in-lane in that layout.
// Scale folding: q,k weights/bias pre-scaled by sqrt(0.125*log2e) so softmax
// runs in log2 domain with NO multiplies (exp2 only).
// ---------------------------------------------------------------------------

typedef float  f32x4  __attribute__((ext_vector_type(4)));
typedef short  s16x4  __attribute__((ext_vector_type(4)));
typedef short  s16x8  __attribute__((ext_vector_type(8)));
typedef __bf16 bf16x8 __attribute__((ext_vector_type(8)));

#define QK_SCALE 0.4246609f   // sqrt(0.125 * log2(e)):  (q*s)·(k*s) = log2e * qk/8

__device__ __forceinline__ f32x4 mfma_bf16_16x16x32(s16x8 a, s16x8 b, f32x4 c){
  return __builtin_amdgcn_mfma_f32_16x16x32_bf16(
      __builtin_bit_cast(bf16x8, a), __builtin_bit_cast(bf16x8, b), c, 0, 0, 0);
}

__device__ __forceinline__ s16x8 cat8(s16x4 lo, s16x4 hi){
  return __builtin_shufflevector(lo, hi, 0,1,2,3,4,5,6,7);
}

__device__ __forceinline__ short f2bf(float v){
  return __builtin_bit_cast(short, static_cast<__bf16>(v));
}

// ---------------------------------------------------------------------------
// GroupNorm stats: one block per (b,g); group = 16 contiguous channels * 1024
__global__ __launch_bounds__(256) void gn_stats_kernel(const float* __restrict__ x,
                                                       float2* __restrict__ stats){
  __shared__ float ss[256], sq[256];
  const int bg = blockIdx.x;
  const float4* base = (const float4*)(x + (size_t)bg * 16384);
  float s = 0.f, q = 0.f;
  #pragma unroll
  for (int i = 0; i < 16; ++i){
    float4 v = base[threadIdx.x + i*256];
    s += v.x + v.y + v.z + v.w;
    q += v.x*v.x + v.y*v.y + v.z*v.z + v.w*v.w;
  }
  ss[threadIdx.x] = s; sq[threadIdx.x] = q;
  __syncthreads();
  for (int off = 128; off > 0; off >>= 1){
    if (threadIdx.x < off){ ss[threadIdx.x] += ss[threadIdx.x+off];
                            sq[threadIdx.x] += sq[threadIdx.x+off]; }
    __syncthreads();
  }
  if (threadIdx.x == 0){
    float mu  = ss[0] * (1.f/16384.f);
    float var = sq[0] * (1.f/16384.f) - mu*mu;   // biased (matches jnp.var)
    stats[bg] = make_float2(mu, rsqrtf(var + 1e-5f));
  }
}

// normalize + affine -> bf16 xnT[b][t][c] (transposed via LDS tile)
__global__ __launch_bounds__(256) void gn_norm_t_kernel(const float* __restrict__ x,
    const float* __restrict__ w, const float* __restrict__ bia,
    const float2* __restrict__ stats, short* __restrict__ xnT){
  const int t0 = blockIdx.x * 64, b = blockIdx.y;
  const int tid = threadIdx.x;
  __shared__ short L[64*68];                 // [c][t] pad->68
  const float* xb = x   + (size_t)b * 524288;
  short*       ob = xnT + (size_t)b * 524288;
  for (int cc = 0; cc < 8; ++cc){
    #pragma unroll
    for (int i = 0; i < 4; ++i){
      const int f  = tid + i*256;            // 0..1023
      const int cl = f >> 4, t4 = (f & 15) * 4;
      const int ch = cc*64 + cl;
      const float2 st = stats[b*32 + (ch >> 4)];
      const float sc = st.y * w[ch];
      const float sh = bia[ch] - st.x * sc;
      float4 v = *(const float4*)(xb + (size_t)ch*1024 + t0 + t4);
      s16x4 o;
      o[0]=f2bf(v.x*sc+sh); o[1]=f2bf(v.y*sc+sh); o[2]=f2bf(v.z*sc+sh); o[3]=f2bf(v.w*sc+sh);
      *(s16x4*)&L[cl*68 + t4] = o;
    }
    __syncthreads();
    #pragma unroll
    for (int i = 0; i < 2; ++i){
      const int g  = tid + i*256;            // 0..511
      const int tl = g >> 3, c8 = g & 7;
      s16x8 o;
      #pragma unroll
      for (int j = 0; j < 8; ++j) o[j] = L[(c8*8 + j)*68 + tl];
      *(s16x8*)(ob + (size_t)(t0 + tl)*512 + cc*64 + c8*8) = o;
    }
    __syncthreads();
  }
}

// fp32 -> bf16; rows r with (r%192)<128 (q,k rows of qkv_w) scaled by qks
__global__ __launch_bounds__(256) void cvt_bf16_kernel(const float* __restrict__ in,
                                                       short* __restrict__ out, int n8,
                                                       float qks){
  const int i = blockIdx.x*256 + threadIdx.x;
  if (i >= n8) return;
  const float s = (((i >> 6) % 192) < 128) ? qks : 1.f;
  const float4* p = (const float4*)in + (size_t)i*2;
  float4 a = p[0], b = p[1];
  s16x8 o;
  o[0]=f2bf(a.x*s); o[1]=f2bf(a.y*s); o[2]=f2bf(a.z*s); o[3]=f2bf(a.w*s);
  o[4]=f2bf(b.x*s); o[5]=f2bf(b.y*s); o[6]=f2bf(b.z*s); o[7]=f2bf(b.w*s);
  *(s16x8*)(out + (size_t)i*8) = o;
}

// ---------------------------------------------------------------------------
// Unified K=512 GEMM, 128x128 tile, BK=32, 4 waves (2x2), 4x4 16x16 frags/wave.
// Frags: contiguous k-map (k=8*lb+j) -> single ds_read_b128, bank-perfect @pad40.
template<int MODE>
__global__ __launch_bounds__(256) void gemm_k512(const short* __restrict__ W,
    const short* __restrict__ act, const float* __restrict__ bias,
    const float* __restrict__ resid, void* __restrict__ outp){
  const int b  = blockIdx.z;
  const int m0 = blockIdx.y * 128;
  const int n0 = blockIdx.x * 128;
  const int tid  = threadIdx.x;
  const int lane = tid & 63, w = tid >> 6;
  const int wm = w >> 1, wn = w & 1;
  const int lm = lane & 15, lb = lane >> 4;

  __shared__ short As[2][128*40];
  __shared__ short Bs[2][128*40];

  const short* actb = act + (size_t)b * 524288;

  auto arow = [&](int r) -> const short* {
    if constexpr (MODE == 0){
      return actb + (size_t)(m0 + r) * 512;
    } else if constexpr (MODE == 1){
      const int m = m0 + r;
      return W + (size_t)(192*(m>>6) + 128 + (m&63)) * 512;
    } else {
      return W + (size_t)(m0 + r) * 512;
    }
  };
  auto brow = [&](int r) -> const short* {
    if constexpr (MODE == 0){
      const int o = n0 + r;
      return W + (size_t)(192*((o>>6)&7) + (o&63) + ((o>=512)?64:0)) * 512;
    } else {
      return actb + (size_t)(n0 + r) * 512;
    }
  };

  uint4 areg[2], breg[2];
  auto load_regs = [&](int t){
    const int k0 = t * 32;
    #pragma unroll
    for (int i = 0; i < 2; ++i){
      const int c = tid + i*256;
      const int r = c >> 2, off = (c & 3) * 8;
      areg[i] = *(const uint4*)(arow(r) + k0 + off);
      breg[i] = *(const uint4*)(brow(r) + k0 + off);
    }
  };
  auto write_lds = [&](int buf){
    #pragma unroll
    for (int i = 0; i < 2; ++i){
      const int c = tid + i*256;
      const int r = c >> 2, off = (c & 3) * 8;
      *(uint4*)&As[buf][r*40 + off] = areg[i];
      *(uint4*)&Bs[buf][r*40 + off] = breg[i];
    }
  };

  f32x4 acc[4][4] = {};
  load_regs(0);
  write_lds(0);

  for (int t = 0; t < 16; ++t){
    if (t + 1 < 16) load_regs(t + 1);
    __syncthreads();
    const int buf = t & 1;

    s16x8 af[4], bf[4];
    #pragma unroll
    for (int ms = 0; ms < 4; ++ms)
      af[ms] = *(const s16x8*)&As[buf][(wm*64 + ms*16 + lm)*40 + 8*lb];
    #pragma unroll
    for (int ns = 0; ns < 4; ++ns)
      bf[ns] = *(const s16x8*)&Bs[buf][(wn*64 + ns*16 + lm)*40 + 8*lb];
    #pragma unroll
    for (int ns = 0; ns < 4; ++ns)
      #pragma unroll
      for (int ms = 0; ms < 4; ++ms)
        acc[ms][ns] = mfma_bf16_16x16x32(af[ms], bf[ns], acc[ms][ns]);

    if (t + 1 < 16) write_lds((t + 1) & 1);
  }

  // C/D: col = lane&15, row = 4*(lane>>4) + reg   (m89)
  const int mo = m0 + wm*64, no = n0 + wn*64;
  if constexpr (MODE == 0){
    short* out = (short*)outp + (size_t)b * 1048576;
    float bn[4];
    #pragma unroll
    for (int ns = 0; ns < 4; ++ns){
      const int o = no + ns*16 + lm;
      bn[ns] = QK_SCALE * bias[192*((o>>6)&7) + (o&63) + ((o>=512)?64:0)];
    }
    #pragma unroll
    for (int ms = 0; ms < 4; ++ms)
      #pragma unroll
      for (int ns = 0; ns < 4; ++ns)
        #pragma unroll
        for (int r = 0; r < 4; ++r){
          const int m = mo + ms*16 + 4*lb + r;
          const int n = no + ns*16 + lm;
          out[(size_t)m*1024 + n] = f2bf(acc[ms][ns][r] + bn[ns]);
        }
  } else if constexpr (MODE == 1){
    short* out = (short*)outp + (size_t)b * 524288;
    float bm[16];
    #pragma unroll
    for (int ms = 0; ms < 4; ++ms)
      #pragma unroll
      for (int r = 0; r < 4; ++r){
        const int m = mo + ms*16 + 4*lb + r;
        bm[ms*4+r] = bias[192*(m>>6) + 128 + (m&63)];
      }
    #pragma unroll
    for (int ms = 0; ms < 4; ++ms)
      #pragma unroll
      for (int ns = 0; ns < 4; ++ns)
        #pragma unroll
        for (int r = 0; r < 4; ++r){
          const int m = mo + ms*16 + 4*lb + r;
          const int n = no + ns*16 + lm;
          out[(size_t)m*1024 + n] = f2bf(acc[ms][ns][r] + bm[ms*4+r]);
        }
  } else {
    float* out = (float*)outp + (size_t)b * 524288;
    const float* xr = resid + (size_t)b * 524288;
    #pragma unroll
    for (int ms = 0; ms < 4; ++ms)
      #pragma unroll
      for (int ns = 0; ns < 4; ++ns)
        #pragma unroll
        for (int r = 0; r < 4; ++r){
          const int m = mo + ms*16 + 4*lb + r;
          const int n = no + ns*16 + lm;
          out[(size_t)m*1024 + n] = acc[ms][ns][r] + bias[m] + xr[(size_t)m*1024 + n];
        }
  }
}

// ---------------------------------------------------------------------------
// Attention v3: 512 blocks (bid = bh + 64*tc -> bid%8 = bh%8 = XCD locality).
// 4 waves x 32t = 128 t per block. K/V double-buffered LDS (reg-staged),
// ONE barrier per iter. Softmax in log2 domain, defer-max THR=8.
__global__ __launch_bounds__(256) void attn3_kernel(const short* __restrict__ qkT,
    const short* __restrict__ vbuf, short* __restrict__ attT){
  const int bid = blockIdx.x;
  const int bh = bid & 63, tc = bid >> 6;
  const int b = bh >> 3, h = bh & 7;
  const int tid = threadIdx.x;
  const int lane = tid & 63, w = tid >> 6;
  const int lm = lane & 15, lb = lane >> 4;
  const int t0 = tc * 128;

  const short* qb = qkT + (size_t)b*1048576 + h*64;          // + t*1024
  const short* kb = qkT + (size_t)b*1048576 + 512 + h*64;    // + s*1024
  const short* vb = vbuf + (size_t)b*524288 + (size_t)(h*64)*1024;  // + c*1024 + s

  __shared__ short Ks[2][64*72];    // [s][c] pad 72 (b128 frags bank-perfect)
  __shared__ short Vs[2][64*68];    // [c][s] pad 68 (b64 pairs bank-perfect)

  // Q frags straight from global (read-once), contiguous k-map
  s16x8 qf[2][2];
  #pragma unroll
  for (int tb = 0; tb < 2; ++tb)
    #pragma unroll
    for (int ks = 0; ks < 2; ++ks)
      qf[tb][ks] = *(const s16x8*)(qb + (size_t)(t0 + w*32 + tb*16 + lm)*1024
                                      + ks*32 + 8*lb);

  uint4 kreg[2], vreg[2];
  auto load_kv = [&](int it){
    const int s0 = it * 64;
    #pragma unroll
    for (int i = 0; i < 2; ++i){
      const int g = tid + i*256, r = g >> 3, c8 = g & 7;
      kreg[i] = *(const uint4*)(kb + (size_t)(s0 + r)*1024 + c8*8);
      vreg[i] = *(const uint4*)(vb + (size_t)r*1024 + s0 + c8*8);
    }
  };
  auto write_kv = [&](int buf){
    #pragma unroll
    for (int i = 0; i < 2; ++i){
      const int g = tid + i*256, r = g >> 3, c8 = g & 7;
      *(uint4*)&Ks[buf][r*72 + c8*8] = kreg[i];
      *(uint2*)&Vs[buf][r*68 + c8*8]     = make_uint2(vreg[i].x, vreg[i].y);
      *(uint2*)&Vs[buf][r*68 + c8*8 + 4] = make_uint2(vreg[i].z, vreg[i].w);
    }
  };

  f32x4 of[2][4] = {};
  float mrun[2] = {-1e30f, -1e30f}, lrun[2] = {0.f, 0.f};
  s16x8 pbf[2][2];

  load_kv(0);
  write_kv(0);

  for (int it = 0; it < 16; ++it){
    if (it + 1 < 16) load_kv(it + 1);
    __syncthreads();
    const int buf = it & 1;

    // QK^T: S'[s][t], contiguous k-map, single b128 K-frags
    f32x4 sf[2][4];
    #pragma unroll
    for (int tb = 0; tb < 2; ++tb)
      #pragma unroll
      for (int ms = 0; ms < 4; ++ms) sf[tb][ms] = 0.f;
    #pragma unroll
    for (int ks = 0; ks < 2; ++ks){
      s16x8 kf[4];
      #pragma unroll
      for (int ms = 0; ms < 4; ++ms)
        kf[ms] = *(const s16x8*)&Ks[buf][(ms*16 + lm)*72 + ks*32 + 8*lb];
      #pragma unroll
      for (int ms = 0; ms < 4; ++ms){
        sf[0][ms] = mfma_bf16_16x16x32(kf[ms], qf[0][ks], sf[0][ms]);
        sf[1][ms] = mfma_bf16_16x16x32(kf[ms], qf[1][ks], sf[1][ms]);
      }
    }

    // online softmax (log2 domain; logits pre-scaled by QK_SCALE^2 fold)
    #pragma unroll
    for (int tb = 0; tb < 2; ++tb){
      float mt = sf[tb][0][0];
      #pragma unroll
      for (int ms = 0; ms < 4; ++ms)
        #pragma unroll
        for (int r = 0; r < 4; ++r)
          if (ms | r) mt = fmaxf(mt, sf[tb][ms][r]);
      mt = fmaxf(mt, __shfl_xor(mt, 16, 64));
      mt = fmaxf(mt, __shfl_xor(mt, 32, 64));
      const bool allskip = __all(mt <= mrun[tb] + 8.f);
      const float mnew = allskip ? mrun[tb] : fmaxf(mrun[tb], mt);
      float p[16];
      float ps = 0.f;
      #pragma unroll
      for (int ms = 0; ms < 4; ++ms)
        #pragma unroll
        for (int r = 0; r < 4; ++r){
          const float e = exp2f(sf[tb][ms][r] - mnew);
          p[ms*4 + r] = e; ps += e;
        }
      ps += __shfl_xor(ps, 16, 64);
      ps += __shfl_xor(ps, 32, 64);
      if (allskip){
        lrun[tb] += ps;
      } else {
        const float alpha = exp2f(mrun[tb] - mnew);
        lrun[tb] = lrun[tb]*alpha + ps;
        mrun[tb] = mnew;
        #pragma unroll
        for (int cs = 0; cs < 4; ++cs) of[tb][cs] *= alpha;
      }
      #pragma unroll
      for (int ks2 = 0; ks2 < 2; ++ks2)
        #pragma unroll
        for (int j = 0; j < 8; ++j)
          pbf[tb][ks2][j] = f2bf(p[8*ks2 + j]);
    }

    // PV: D[c][t] = mfma(A=V rows, B=P'); old k-map (P' in-lane), b64 pairs
    #pragma unroll
    for (int ks2 = 0; ks2 < 2; ++ks2)
      #pragma unroll
      for (int cs = 0; cs < 4; ++cs){
        const short* pV = &Vs[buf][(cs*16 + lm)*68 + ks2*32 + 4*lb];
        s16x8 vf = cat8(*(const s16x4*)pV, *(const s16x4*)(pV + 16));
        of[0][cs] = mfma_bf16_16x16x32(vf, pbf[0][ks2], of[0][cs]);
        of[1][cs] = mfma_bf16_16x16x32(vf, pbf[1][ks2], of[1][cs]);
      }

    if (it + 1 < 16) write_kv((it + 1) & 1);
  }

  // epilogue: of[tb][cs][r] = A_att[c = cs*16+4lb+r][t = w*32+tb*16+lm];
  // transpose via LDS (reuse Ks: 128x72 shorts) -> attT[b][t][c] coalesced.
  __syncthreads();
  short* Tl = &Ks[0][0];
  const float inv0 = 1.f / lrun[0], inv1 = 1.f / lrun[1];
  #pragma unroll
  for (int tb = 0; tb < 2; ++tb)
    #pragma unroll
    for (int cs = 0; cs < 4; ++cs)
      #pragma unroll
      for (int r = 0; r < 4; ++r)
        Tl[(w*32 + tb*16 + lm)*72 + cs*16 + 4*lb + r] =
            f2bf(of[tb][cs][r] * (tb ? inv1 : inv0));
  __syncthreads();
  short* outb = attT + (size_t)b*524288 + (size_t)t0*512 + h*64;
  #pragma unroll
  for (int i = 0; i < 4; ++i){
    const int g = tid + i*256, r = g >> 3, c8 = g & 7;
    *(uint4*)(outb + (size_t)r*512 + c8*8) = *(const uint4*)&Tl[r*72 + c8*8];
  }
}

// ---------------------------------------------------------------------------
extern "C" void kernel_launch(void* const* d_in, const int* in_sizes, int n_in,
                              void* d_out, int out_size, void* d_ws, size_t ws_size,
                              hipStream_t stream){
  const float* x      = (const float*)d_in[0];
  const float* norm_w = (const float*)d_in[1];
  const float* norm_b = (const float*)d_in[2];
  const float* qkv_w  = (const float*)d_in[3];
  const float* qkv_b  = (const float*)d_in[4];
  const float* proj_w = (const float*)d_in[5];
  const float* proj_b = (const float*)d_in[6];

  char* ws = (char*)d_ws;
  float2* stats = (float2*)(ws);                                   //   4 KB
  short*  xnT   = (short*)(ws + 4096);                             //   8 MiB
  short*  qwb   = (short*)(ws + 4096 + 8388608);                   // 1.5 MiB
  short*  pwb   = (short*)(ws + 4096 + 8388608 + 1572864);         // 0.5 MiB
  short*  qkT   = (short*)(ws + 4096 + 8388608 + 1572864 + 524288);            // 16 MiB
  short*  vbuf  = (short*)(ws + 4096 + 8388608 + 1572864 + 524288 + 16777216); //  8 MiB
  short*  attT  = (short*)(ws + 4096 + 8388608 + 1572864 + 524288 + 16777216 + 8388608); // 8 MiB

  gn_stats_kernel<<<dim3(256), dim3(256), 0, stream>>>(x, stats);
  gn_norm_t_kernel<<<dim3(16, 8), dim3(256), 0, stream>>>(x, norm_w, norm_b, stats, xnT);
  cvt_bf16_kernel<<<dim3(384), dim3(256), 0, stream>>>(qkv_w, qwb, 98304, QK_SCALE);
  cvt_bf16_kernel<<<dim3(128), dim3(256), 0, stream>>>(proj_w, pwb, 32768, 1.f);
  gemm_k512<0><<<dim3(8, 8, 8), dim3(256), 0, stream>>>(qwb, xnT, qkv_b, nullptr, (void*)qkT);
  gemm_k512<1><<<dim3(8, 4, 8), dim3(256), 0, stream>>>(qwb, xnT, qkv_b, nullptr, (void*)vbuf);
  attn3_kernel<<<dim3(512), dim3(256), 0, stream>>>(qkT, vbuf, attT);
  gemm_k512<2><<<dim3(8, 4, 8), dim3(256), 0, stream>>>(pwb, attT, proj_b, x, d_out);
}